// Round 1
// baseline (89.748 us; speedup 1.0000x reference)
//
#include <hip/hip_runtime.h>

#define NROWS 8192
#define TCOLS 256
constexpr float SIGMA_INV = 0.01f;   // 1/100

// ---------------------------------------------------------------------------
// k1: per-row cumsum + L1 partials + column-bin accumulation G[k]
//   G[k] = sum_{j : ev[j] && y[j] > k} exp(F1[j,k]/SIGMA)
//   c[i] = ev[i] ? exp(-A[i]/SIGMA) : 0
//   l1acc += -status*log(p_at_y) - (1-status)*log(1-A)
// One wave (64 lanes) per row; each lane owns 4 contiguous columns (float4).
// ---------------------------------------------------------------------------
__global__ __launch_bounds__(256) void surv_k1(
    const float* __restrict__ yp, const int* __restrict__ y,
    const float* __restrict__ st, float* __restrict__ G,
    float* __restrict__ l1acc, float* __restrict__ c)
{
    // Gw[wave][t][lane] holds the partial for column k = lane*4 + t.
    // lane-major inner dim -> conflict-free LDS (stride-1 across lanes).
    __shared__ float Gw[4][4][64];
    const int tid  = threadIdx.x;
    const int wave = tid >> 6;
    const int lane = tid & 63;

    // each wave zeroes only its own slice -> no barrier needed before use
    Gw[wave][0][lane] = 0.f;
    Gw[wave][1][lane] = 0.f;
    Gw[wave][2][lane] = 0.f;
    Gw[wave][3][lane] = 0.f;

    float l1 = 0.f;
    const int row0 = blockIdx.x * 32;   // 256 blocks * 32 rows = 8192

    #pragma unroll 2
    for (int r = 0; r < 8; ++r) {
        const int row = row0 + wave + 4 * r;

        const float4 v =
            reinterpret_cast<const float4*>(yp + (size_t)row * TCOLS)[lane];

        // inclusive prefix within the 4 local elements
        const float s0 = v.x;
        const float s1 = s0 + v.y;
        const float s2 = s1 + v.z;
        const float s3 = s2 + v.w;

        // 64-lane inclusive shuffle scan of per-lane totals
        float x = s3;
        #pragma unroll
        for (int d = 1; d < 64; d <<= 1) {
            const float t = __shfl_up(x, d);
            if (lane >= d) x += t;
        }
        const float pre = x - s3;   // exclusive prefix for this lane
        const float f0 = pre + s0, f1 = pre + s1, f2 = pre + s2, f3 = pre + s3;

        const int   yi  = y[row];
        const float sti = st[row];
        const bool  ev  = (sti > 0.5f);

        // A = F1[row, yi], p = y_pred[row, yi]  (yi is wave-uniform)
        const int yl = yi >> 2, ye = yi & 3;
        const float fa = (ye == 0) ? f0 : (ye == 1) ? f1 : (ye == 2) ? f2 : f3;
        const float va = (ye == 0) ? v.x : (ye == 1) ? v.y : (ye == 2) ? v.z : v.w;
        const float A = __shfl(fa, yl);
        const float p = __shfl(va, yl);

        if (lane == 0) {
            l1 += -sti * __logf(p) - (1.f - sti) * __logf(1.f - A);
            c[row] = ev ? __expf(-A * SIGMA_INV) : 0.f;
        }

        if (ev) {
            const int k0 = lane << 2;
            if (k0     < yi) Gw[wave][0][lane] += __expf(f0 * SIGMA_INV);
            if (k0 + 1 < yi) Gw[wave][1][lane] += __expf(f1 * SIGMA_INV);
            if (k0 + 2 < yi) Gw[wave][2][lane] += __expf(f2 * SIGMA_INV);
            if (k0 + 3 < yi) Gw[wave][3][lane] += __expf(f3 * SIGMA_INV);
        }
    }

    __syncthreads();
    // combine 4 wave-partials; bin k = tid -> Gw[w][tid&3][tid>>2]
    const float g = Gw[0][tid & 3][tid >> 2] + Gw[1][tid & 3][tid >> 2]
                  + Gw[2][tid & 3][tid >> 2] + Gw[3][tid & 3][tid >> 2];
    atomicAdd(&G[tid], g);
    if (lane == 0) atomicAdd(l1acc, l1);
}

// ---------------------------------------------------------------------------
// k2: out[0] = l1 + sum_i c[i] * G[y[i]]   (single block, G cached in LDS)
// ---------------------------------------------------------------------------
__global__ __launch_bounds__(256) void surv_k2(
    const float* __restrict__ G, const float* __restrict__ l1acc,
    const float* __restrict__ c, const int* __restrict__ y,
    float* __restrict__ out)
{
    __shared__ float Gs[256];
    __shared__ float wsum[4];
    const int tid = threadIdx.x;
    Gs[tid] = G[tid];
    __syncthreads();

    float s = 0.f;
    for (int i = tid; i < NROWS; i += 256)
        s += c[i] * Gs[y[i]];

    #pragma unroll
    for (int d = 32; d; d >>= 1) s += __shfl_down(s, d);
    if ((tid & 63) == 0) wsum[tid >> 6] = s;
    __syncthreads();
    if (tid == 0)
        out[0] = wsum[0] + wsum[1] + wsum[2] + wsum[3] + l1acc[0];
}

extern "C" void kernel_launch(void* const* d_in, const int* in_sizes, int n_in,
                              void* d_out, int out_size, void* d_ws, size_t ws_size,
                              hipStream_t stream) {
    const float* yp = (const float*)d_in[0];   // y_pred (8192 x 256) f32
    const int*   y  = (const int*)d_in[1];     // y (8192) int
    const float* st = (const float*)d_in[2];   // status (8192) f32

    float* G     = (float*)d_ws;               // 256 floats
    float* l1acc = G + 256;                    // 1 float (padded region)
    float* c     = G + 512;                    // 8192 floats
    float* out   = (float*)d_out;

    // zero G + l1acc (ws is poisoned 0xAA before every launch)
    hipMemsetAsync(d_ws, 0, 2048, stream);

    surv_k1<<<256, 256, 0, stream>>>(yp, y, st, G, l1acc, c);
    surv_k2<<<1, 256, 0, stream>>>(G, l1acc, c, y, out);
}